// Round 1
// baseline (2098.471 us; speedup 1.0000x reference)
//
#include <hip/hip_runtime.h>
#include <cstdint>
#include <cstddef>

#define BATCH 512
#define TSTEPS 20
#define HD 128
#define VOC 5000

__device__ __forceinline__ float sigm(float x){ return 1.f/(1.f+expf(-x)); }

__device__ __forceinline__ unsigned long long enc_key(float x, int v){
  unsigned u = __float_as_uint(x);
  u = (u & 0x80000000u) ? ~u : (u | 0x80000000u);   // orderable-uint map
  return ((unsigned long long)u << 32) | (unsigned)(0xFFFF - v); // smaller v wins ties
}
__device__ __forceinline__ unsigned long long umax64(unsigned long long a, unsigned long long b){
  return a > b ? a : b;
}

// ---------------- conv1 + BN + ReLU + maxpool3 ----------------
// in  (512,19,3000), W1 (32,19,7), stride 2 pad 3 -> (512,32,1500) -> pool -> (512,32,500)
__global__ __launch_bounds__(256) void k_conv1(
    const float* __restrict__ x, const float* __restrict__ W,
    const float* __restrict__ bias, const float* __restrict__ g,
    const float* __restrict__ beta, const float* __restrict__ m,
    const float* __restrict__ vv, float* __restrict__ y)
{
  __shared__ float xt[19*392];     // input tile, local pos = 6*dlp + 2s + k
  __shared__ float wt[133*36];     // [ci*7+k][co], stride 36 (align + bank spread)
  __shared__ float sc[32], sh[32];
  const int b   = blockIdx.y;
  const int lp0 = blockIdx.x * 64;
  const int tid = threadIdx.x;
  const float* xb = x + (size_t)b*19*3000;
  const int base = 6*lp0 - 3;
  for (int i = tid; i < 19*392; i += 256){
    int ci = i / 392, p = i - ci*392;
    int gp = base + p;
    xt[i] = (gp >= 0 && gp < 3000) ? xb[ci*3000 + gp] : 0.f;
  }
  for (int i = tid; i < 32*133; i += 256){
    int co = i / 133, r = i - co*133;
    wt[r*36 + co] = W[i];
  }
  if (tid < 32){
    float s = g[tid] * rsqrtf(vv[tid] + 1e-5f);
    sc[tid] = s;
    sh[tid] = (bias[tid] - m[tid]) * s + beta[tid];
  }
  __syncthreads();
  const int lane = tid & 63, cog = tid >> 6;   // 4 groups x 8 co
  const int lp = lp0 + lane;
  float acc[8][3];
  #pragma unroll
  for (int a=0;a<8;a++){ acc[a][0]=0.f; acc[a][1]=0.f; acc[a][2]=0.f; }
  const int xb0 = 6*lane;
  for (int ci = 0; ci < 19; ci++){
    #pragma unroll
    for (int k = 0; k < 7; k++){
      const float* wr = &wt[(ci*7+k)*36 + cog*8];
      float4 w0 = *(const float4*)wr;
      float4 w1 = *(const float4*)(wr+4);
      const float* xr = &xt[ci*392 + xb0 + k];
      float x0 = xr[0], x1 = xr[2], x2 = xr[4];
      float w8[8] = {w0.x,w0.y,w0.z,w0.w,w1.x,w1.y,w1.z,w1.w};
      #pragma unroll
      for (int a=0;a<8;a++){
        acc[a][0] = fmaf(w8[a], x0, acc[a][0]);
        acc[a][1] = fmaf(w8[a], x1, acc[a][1]);
        acc[a][2] = fmaf(w8[a], x2, acc[a][2]);
      }
    }
  }
  if (lp < 500){
    #pragma unroll
    for (int a=0;a<8;a++){
      int co = cog*8 + a;
      float s = sc[co], t0 = sh[co];
      float r0 = fmaxf(fmaf(acc[a][0], s, t0), 0.f);
      float r1 = fmaxf(fmaf(acc[a][1], s, t0), 0.f);
      float r2 = fmaxf(fmaf(acc[a][2], s, t0), 0.f);
      y[((size_t)b*32 + co)*500 + lp] = fmaxf(r0, fmaxf(r1, r2));
    }
  }
}

// ---------------- conv2 + BN + ReLU + maxpool3 ----------------
// in (512,32,500), W2 (64,32,5), stride 2 pad 2 -> (512,64,250) -> pool (83, uses 249)
__global__ __launch_bounds__(512) void k_conv2(
    const float* __restrict__ y1, const float* __restrict__ W,
    const float* __restrict__ bias, const float* __restrict__ g,
    const float* __restrict__ beta, const float* __restrict__ m,
    const float* __restrict__ vv, float* __restrict__ y2)
{
  __shared__ float xt[32*502];     // pos staged at +2 (pad=2)
  __shared__ float wt[160*68];     // [ci*5+k][co]
  __shared__ float sc[64], sh[64];
  const int b = blockIdx.x;
  const int tid = threadIdx.x;
  const float* xb = y1 + (size_t)b*32*500;
  for (int i = tid; i < 32*502; i += 512){
    int ci = i / 502, p = i - ci*502;
    int gp = p - 2;
    xt[i] = (gp >= 0 && gp < 500) ? xb[ci*500 + gp] : 0.f;
  }
  for (int i = tid; i < 64*160; i += 512){
    int co = i / 160, r = i - co*160;
    wt[r*68 + co] = W[i];
  }
  if (tid < 64){
    float s = g[tid]*rsqrtf(vv[tid]+1e-5f);
    sc[tid] = s; sh[tid] = (bias[tid]-m[tid])*s + beta[tid];
  }
  __syncthreads();
  const int lane = tid & 63, wg = tid >> 6;   // 8 groups x 8 co
  for (int half = 0; half < 2; half++){
    int lp = half*64 + lane;
    bool act = lp < 83;
    int lpc = act ? lp : 0;
    float acc[8][3];
    #pragma unroll
    for (int a=0;a<8;a++){ acc[a][0]=0.f; acc[a][1]=0.f; acc[a][2]=0.f; }
    for (int ci = 0; ci < 32; ci++){
      #pragma unroll
      for (int k = 0; k < 5; k++){
        const float* wr = &wt[(ci*5+k)*68 + wg*8];
        float4 w0 = *(const float4*)wr;
        float4 w1 = *(const float4*)(wr+4);
        const float* xr = &xt[ci*502 + 6*lpc + k];   // idx = 6lp + 2s + k (pos+2)
        float x0 = xr[0], x1 = xr[2], x2 = xr[4];
        float w8[8] = {w0.x,w0.y,w0.z,w0.w,w1.x,w1.y,w1.z,w1.w};
        #pragma unroll
        for (int a=0;a<8;a++){
          acc[a][0] = fmaf(w8[a], x0, acc[a][0]);
          acc[a][1] = fmaf(w8[a], x1, acc[a][1]);
          acc[a][2] = fmaf(w8[a], x2, acc[a][2]);
        }
      }
    }
    if (act){
      #pragma unroll
      for (int a=0;a<8;a++){
        int co = wg*8 + a;
        float s = sc[co], t0 = sh[co];
        float r0 = fmaxf(fmaf(acc[a][0], s, t0), 0.f);
        float r1 = fmaxf(fmaf(acc[a][1], s, t0), 0.f);
        float r2 = fmaxf(fmaf(acc[a][2], s, t0), 0.f);
        y2[((size_t)b*64 + co)*83 + lp] = fmaxf(r0, fmaxf(r1, r2));
      }
    }
  }
}

// ---------------- conv3 + BN + ReLU + mean ----------------
// in (512,64,83), W3 (128,64,3), stride 2 pad 1 -> (512,128,42) -> mean -> (512,128)
__global__ __launch_bounds__(512) void k_conv3(
    const float* __restrict__ y2, const float* __restrict__ W,
    const float* __restrict__ bias, const float* __restrict__ g,
    const float* __restrict__ beta, const float* __restrict__ m,
    const float* __restrict__ vv, float* __restrict__ feat)
{
  __shared__ float xt[64*85];      // pos staged at +1 (pad=1)
  __shared__ float wt[192*132];    // [ci*3+k][co], stride 132
  __shared__ float sc[128], sh[128];
  __shared__ float ps[4][128];
  const int b = blockIdx.x;
  const int tid = threadIdx.x;
  const float* xb = y2 + (size_t)b*64*83;
  for (int i = tid; i < 64*85; i += 512){
    int ci = i / 85, p = i - ci*85;
    int gp = p - 1;
    xt[i] = (gp >= 0 && gp < 83) ? xb[ci*83 + gp] : 0.f;
  }
  for (int i = tid; i < 128*192; i += 512){
    int co = i / 192, r = i - co*192;
    wt[r*132 + co] = W[i];
  }
  if (tid < 128){
    float s = g[tid]*rsqrtf(vv[tid]+1e-5f);
    sc[tid] = s; sh[tid] = (bias[tid]-m[tid])*s + beta[tid];
  }
  __syncthreads();
  const int co = tid & 127, q = tid >> 7;     // 4 l-phases
  float s = sc[co], t0 = sh[co];
  float acc = 0.f;
  for (int l = q; l < 42; l += 4){
    float s0 = 0.f, s1 = 0.f;
    for (int ci = 0; ci < 64; ci += 2){
      #pragma unroll
      for (int k = 0; k < 3; k++){
        s0 = fmaf(wt[(ci*3+k)*132 + co],     xt[ci*85 + 2*l + k],     s0);
        s1 = fmaf(wt[((ci+1)*3+k)*132 + co], xt[(ci+1)*85 + 2*l + k], s1);
      }
    }
    acc += fmaxf(fmaf(s0 + s1, s, t0), 0.f);
  }
  ps[q][co] = acc;
  __syncthreads();
  if (tid < 128){
    feat[(size_t)b*128 + tid] = (ps[0][tid]+ps[1][tid]+ps[2][tid]+ps[3][tid]) * (1.f/42.f);
  }
}

// ---------------- fused 2-layer LSTM cell (one decode step) ----------------
__device__ __forceinline__ void accum_dot(const float4* __restrict__ wr,
                                          const float (*xs)[256], int off,
                                          float& a0, float& a1, float& a2, float& a3)
{
  #pragma unroll 8
  for (int k = 0; k < 32; k++){
    float4 w = wr[k];
    float4 x0 = *(const float4*)&xs[0][off + 4*k];
    float4 x1 = *(const float4*)&xs[1][off + 4*k];
    float4 x2 = *(const float4*)&xs[2][off + 4*k];
    float4 x3 = *(const float4*)&xs[3][off + 4*k];
    a0 = fmaf(w.x,x0.x, fmaf(w.y,x0.y, fmaf(w.z,x0.z, fmaf(w.w,x0.w, a0))));
    a1 = fmaf(w.x,x1.x, fmaf(w.y,x1.y, fmaf(w.z,x1.z, fmaf(w.w,x1.w, a1))));
    a2 = fmaf(w.x,x2.x, fmaf(w.y,x2.y, fmaf(w.z,x2.z, fmaf(w.w,x2.w, a2))));
    a3 = fmaf(w.x,x3.x, fmaf(w.y,x3.y, fmaf(w.z,x3.z, fmaf(w.w,x3.w, a3))));
  }
}

__global__ __launch_bounds__(512) void k_cells(
    int t, const float* __restrict__ feat, const float* __restrict__ emb,
    const float* __restrict__ Wih0, const float* __restrict__ Whh0,
    const float* __restrict__ bih0, const float* __restrict__ bhh0,
    const float* __restrict__ Wih1, const float* __restrict__ Whh1,
    const float* __restrict__ bih1, const float* __restrict__ bhh1,
    float* __restrict__ h1, float* __restrict__ c1,
    float* __restrict__ h2, float* __restrict__ c2,
    unsigned long long* __restrict__ slots)
{
  __shared__ float xs[4][256];     // [e|h1] then [h1new|h2prev]
  __shared__ float zs[4][512];
  __shared__ float h2p[4][128];
  __shared__ int toks[4];
  const int b0 = blockIdx.x * 4;
  const int tid = threadIdx.x;
  if (tid < 4){
    int tok = 0;
    if (t > 0) tok = 0xFFFF - (int)(slots[b0+tid] & 0xFFFFFFFFull);
    slots[b0+tid] = 0ull;           // reset for this step's argmax
    toks[tid] = tok;
  }
  __syncthreads();
  for (int i = tid; i < 4*256; i += 512){
    int bi = i >> 8, j = i & 255;
    float v;
    if (j < 128) v = emb[(size_t)toks[bi]*128 + j];
    else         v = (t==0) ? feat[(size_t)(b0+bi)*128 + (j-128)]
                            : h1[(size_t)(b0+bi)*128 + (j-128)];
    xs[bi][j] = v;
  }
  for (int i = tid; i < 4*128; i += 512){
    int bi = i >> 7, j = i & 127;
    h2p[bi][j] = (t==0) ? feat[(size_t)(b0+bi)*128 + j] : h2[(size_t)(b0+bi)*128 + j];
  }
  __syncthreads();
  { // layer 1: z = [e|h1] @ [Wih0|Whh0]^T + b
    int j = tid;
    float bz = bih0[j] + bhh0[j];
    float a0=bz,a1=bz,a2=bz,a3=bz;
    accum_dot((const float4*)(Wih0 + (size_t)j*128), xs, 0,   a0,a1,a2,a3);
    accum_dot((const float4*)(Whh0 + (size_t)j*128), xs, 128, a0,a1,a2,a3);
    zs[0][j]=a0; zs[1][j]=a1; zs[2][j]=a2; zs[3][j]=a3;
  }
  __syncthreads();
  { // gates layer 1
    int bi = tid >> 7, j = tid & 127;
    int b = b0 + bi;
    float zi = zs[bi][j], zf = zs[bi][j+128], zg = zs[bi][j+256], zo = zs[bi][j+384];
    float cp = (t==0) ? 0.f : c1[(size_t)b*128 + j];
    float c = sigm(zf)*cp + sigm(zi)*tanhf(zg);
    float hh = sigm(zo)*tanhf(c);
    c1[(size_t)b*128+j] = c;
    h1[(size_t)b*128+j] = hh;
    xs[bi][j] = hh;
    xs[bi][128+j] = h2p[bi][j];
  }
  __syncthreads();
  { // layer 2
    int j = tid;
    float bz = bih1[j] + bhh1[j];
    float a0=bz,a1=bz,a2=bz,a3=bz;
    accum_dot((const float4*)(Wih1 + (size_t)j*128), xs, 0,   a0,a1,a2,a3);
    accum_dot((const float4*)(Whh1 + (size_t)j*128), xs, 128, a0,a1,a2,a3);
    zs[0][j]=a0; zs[1][j]=a1; zs[2][j]=a2; zs[3][j]=a3;
  }
  __syncthreads();
  { // gates layer 2
    int bi = tid >> 7, j = tid & 127;
    int b = b0 + bi;
    float zi = zs[bi][j], zf = zs[bi][j+128], zg = zs[bi][j+256], zo = zs[bi][j+384];
    float cp = (t==0) ? 0.f : c2[(size_t)b*128 + j];
    float c = sigm(zf)*cp + sigm(zi)*tanhf(zg);
    float hh = sigm(zo)*tanhf(c);
    c2[(size_t)b*128+j] = c;
    h2[(size_t)b*128+j] = hh;
  }
}

// ---------------- logits + write + argmax(atomicMax slots) ----------------
__global__ __launch_bounds__(256) void k_logits(
    int t, const float* __restrict__ h2, const float* __restrict__ Wp,
    const float* __restrict__ bp, float* __restrict__ out,
    unsigned long long* __restrict__ slots)
{
  __shared__ float hs[16][128];
  __shared__ unsigned long long warr[16][4];
  const int b0 = blockIdx.y * 16;
  const int v0 = blockIdx.x * 512;
  const int tid = threadIdx.x;
  for (int i = tid; i < 16*128; i += 256){
    int bi = i >> 7, j = i & 127;
    hs[bi][j] = h2[(size_t)(b0+bi)*128 + j];
  }
  __syncthreads();
  unsigned long long best[16];
  #pragma unroll
  for (int i=0;i<16;i++) best[i] = 0ull;
  for (int rep = 0; rep < 2; rep++){
    int v = v0 + rep*256 + tid;
    if (v < VOC){
      const float4* wr = (const float4*)(Wp + (size_t)v*128);
      float bv = bp[v];
      float acc[16];
      #pragma unroll
      for (int i=0;i<16;i++) acc[i] = bv;
      for (int k = 0; k < 32; k++){
        float4 w = wr[k];
        #pragma unroll
        for (int i=0;i<16;i++){
          float4 a = *(const float4*)&hs[i][4*k];
          acc[i] = fmaf(w.x,a.x, fmaf(w.y,a.y, fmaf(w.z,a.z, fmaf(w.w,a.w, acc[i]))));
        }
      }
      #pragma unroll
      for (int i=0;i<16;i++){
        out[((size_t)(b0+i)*TSTEPS + t)*VOC + v] = acc[i];
        best[i] = umax64(best[i], enc_key(acc[i], v));
      }
    }
  }
  #pragma unroll
  for (int i=0;i<16;i++){
    unsigned long long k = best[i];
    for (int off = 32; off; off >>= 1){
      unsigned long long o = __shfl_xor(k, off, 64);
      k = umax64(k, o);
    }
    best[i] = k;
  }
  int lane = tid & 63, wid = tid >> 6;
  if (lane == 0){
    #pragma unroll
    for (int i=0;i<16;i++) warr[i][wid] = best[i];
  }
  __syncthreads();
  if (tid < 16){
    unsigned long long k = umax64(umax64(warr[tid][0], warr[tid][1]),
                                  umax64(warr[tid][2], warr[tid][3]));
    atomicMax(&slots[b0+tid], k);
  }
}

extern "C" void kernel_launch(void* const* d_in, const int* in_sizes, int n_in,
                              void* d_out, int out_size, void* d_ws, size_t ws_size,
                              hipStream_t stream)
{
  (void)in_sizes; (void)n_in; (void)out_size; (void)ws_size;
  const float* eeg  = (const float*)d_in[0];
  // d_in[1] = target_length (int scalar) — fixed at 20
  const float* W1   = (const float*)d_in[2];
  const float* b1   = (const float*)d_in[3];
  const float* g1   = (const float*)d_in[4];
  const float* be1  = (const float*)d_in[5];
  const float* m1   = (const float*)d_in[6];
  const float* v1   = (const float*)d_in[7];
  const float* W2   = (const float*)d_in[8];
  const float* b2   = (const float*)d_in[9];
  const float* g2   = (const float*)d_in[10];
  const float* be2  = (const float*)d_in[11];
  const float* m2   = (const float*)d_in[12];
  const float* v2   = (const float*)d_in[13];
  const float* W3   = (const float*)d_in[14];
  const float* b3   = (const float*)d_in[15];
  const float* g3   = (const float*)d_in[16];
  const float* be3  = (const float*)d_in[17];
  const float* m3   = (const float*)d_in[18];
  const float* v3   = (const float*)d_in[19];
  const float* emb  = (const float*)d_in[20];
  const float* Wih0 = (const float*)d_in[21];
  const float* Whh0 = (const float*)d_in[22];
  const float* bih0 = (const float*)d_in[23];
  const float* bhh0 = (const float*)d_in[24];
  const float* Wih1 = (const float*)d_in[25];
  const float* Whh1 = (const float*)d_in[26];
  const float* bih1 = (const float*)d_in[27];
  const float* bhh1 = (const float*)d_in[28];
  const float* Wp   = (const float*)d_in[29];
  const float* bp   = (const float*)d_in[30];
  float* out = (float*)d_out;

  // conv activations aliased into d_out (consumed before first logits write)
  float* y1 = out;                       // 512*32*500  = 8,192,000 f
  float* y2 = out + 8192000;             // 512*64*83   = 2,719,744 f
  // small state in ws
  float* ws   = (float*)d_ws;
  float* feat = ws;                      // 65536 f
  float* h1   = feat + 65536;
  float* c1   = h1 + 65536;
  float* h2   = c1 + 65536;
  float* c2   = h2 + 65536;
  unsigned long long* slots = (unsigned long long*)(c2 + 65536);

  k_conv1<<<dim3(8, BATCH), 256, 0, stream>>>(eeg, W1, b1, g1, be1, m1, v1, y1);
  k_conv2<<<BATCH, 512, 0, stream>>>(y1, W2, b2, g2, be2, m2, v2, y2);
  k_conv3<<<BATCH, 512, 0, stream>>>(y2, W3, b3, g3, be3, m3, v3, feat);
  for (int t = 0; t < TSTEPS; t++){
    k_cells<<<128, 512, 0, stream>>>(t, feat, emb, Wih0, Whh0, bih0, bhh0,
                                     Wih1, Whh1, bih1, bhh1, h1, c1, h2, c2, slots);
    k_logits<<<dim3(10, 32), 256, 0, stream>>>(t, h2, Wp, bp, out, slots);
  }
}

// Round 3
// 1582.760 us; speedup vs baseline: 1.3258x; 1.3258x over previous
//
#include <hip/hip_runtime.h>
#include <cstdint>
#include <cstddef>

#define TSTEPS 20
#define VOC 5000

typedef unsigned long long ull;

__device__ __forceinline__ float sigm(float x){ return 1.f/(1.f+expf(-x)); }

__device__ __forceinline__ ull enc_key(float x, int v){
  unsigned u = __float_as_uint(x);
  u = (u & 0x80000000u) ? ~u : (u | 0x80000000u);   // orderable-uint map
  return ((ull)u << 32) | (unsigned)(0xFFFF - v);   // smaller v wins ties
}
__device__ __forceinline__ ull umax64(ull a, ull b){ return a > b ? a : b; }

// ---------------- weight repack: k-chunked, lane-coalesced float4 ----------------
// W4T[kc][g][4] : W4T[kc*2048 + g*4 + j] = Wcat[g][4*kc + j]  (Wcat = [Wih|Whh], K=256)
// Wp4T[kc][v][4]: Wp4T[kc*20000 + v*4 + j] = Wp[v][4*kc + j]  (K=128)
__global__ __launch_bounds__(256) void k_prep(
    const float* __restrict__ Wih0, const float* __restrict__ Whh0,
    const float* __restrict__ Wih1, const float* __restrict__ Whh1,
    const float* __restrict__ Wp,
    float* __restrict__ W4T0, float* __restrict__ W4T1, float* __restrict__ Wp4T)
{
  int idx = blockIdx.x*256 + threadIdx.x;
  if (idx < 65536){
    int li = idx >> 15;
    int r  = idx & 32767;
    int g = r >> 6, kc = r & 63;
    const float* src = (kc < 32) ? (li ? Wih1 : Wih0) : (li ? Whh1 : Whh0);
    float4 w = *(const float4*)(src + (size_t)g*128 + (kc & 31)*4);
    float* dst = li ? W4T1 : W4T0;
    *(float4*)(dst + (size_t)kc*2048 + g*4) = w;
  } else {
    int r = idx - 65536;
    if (r < 160000){
      int v = r >> 5, kc = r & 31;
      float4 w = *(const float4*)(Wp + (size_t)v*128 + kc*4);
      *(float4*)(Wp4T + (size_t)kc*20000 + v*4) = w;
    }
  }
}

// ---------------- conv1 + BN + ReLU + maxpool3 ----------------
// in (512,19,3000), W1 (32,19,7), s2 p3 -> (512,32,1500) -> pool -> (512,32,500)
// block: 256 thr = 64 lanes x {cog(2) x lph(2)}; 16 co x 1 lp per thread, lp-tile 128
__global__ __launch_bounds__(256) void k_conv1(
    const float* __restrict__ x, const float* __restrict__ W,
    const float* __restrict__ bias, const float* __restrict__ g,
    const float* __restrict__ beta, const float* __restrict__ m,
    const float* __restrict__ vv, float* __restrict__ y)
{
  __shared__ float xt[19*776];
  __shared__ float wt[133*36];
  __shared__ float sc[32], sh[32];
  const int b = blockIdx.y, lp0 = blockIdx.x*128, tid = threadIdx.x;
  const float* xb = x + (size_t)b*19*3000;
  const int base = 6*lp0 - 3;
  for (int i = tid; i < 19*776; i += 256){
    int ci = i/776, p = i - ci*776;
    int gp = base + p;
    xt[i] = (gp >= 0 && gp < 3000) ? xb[ci*3000 + gp] : 0.f;
  }
  for (int i = tid; i < 4256; i += 256){
    int co = i/133, r = i - co*133;
    wt[r*36 + co] = W[i];
  }
  if (tid < 32){
    float s = g[tid]*rsqrtf(vv[tid]+1e-5f);
    sc[tid] = s; sh[tid] = (bias[tid]-m[tid])*s + beta[tid];
  }
  __syncthreads();
  const int lane = tid & 63, wvi = tid >> 6;
  const int cog = wvi & 1, lph = wvi >> 1;
  const int lpl = lph*64 + lane, lp = lp0 + lpl;
  float acc[16][3];
  #pragma unroll
  for (int a=0;a<16;a++){ acc[a][0]=0.f; acc[a][1]=0.f; acc[a][2]=0.f; }
  for (int ci = 0; ci < 19; ci++){
    const float2* xp = (const float2*)&xt[ci*776 + 6*lpl];
    float xx[12];
    #pragma unroll
    for (int j=0;j<6;j++){ float2 t2 = xp[j]; xx[2*j]=t2.x; xx[2*j+1]=t2.y; }
    #pragma unroll
    for (int k=0;k<7;k++){
      const float4* wp4 = (const float4*)&wt[(ci*7+k)*36 + cog*16];
      float4 w0=wp4[0], w1=wp4[1], w2=wp4[2], w3=wp4[3];
      float w16[16] = {w0.x,w0.y,w0.z,w0.w, w1.x,w1.y,w1.z,w1.w,
                       w2.x,w2.y,w2.z,w2.w, w3.x,w3.y,w3.z,w3.w};
      #pragma unroll
      for (int a=0;a<16;a++){
        acc[a][0] = fmaf(w16[a], xx[k],   acc[a][0]);
        acc[a][1] = fmaf(w16[a], xx[k+2], acc[a][1]);
        acc[a][2] = fmaf(w16[a], xx[k+4], acc[a][2]);
      }
    }
  }
  if (lp < 500){
    #pragma unroll
    for (int a=0;a<16;a++){
      int co = cog*16 + a;
      float s = sc[co], t0 = sh[co];
      float r0 = fmaxf(fmaf(acc[a][0], s, t0), 0.f);
      float r1 = fmaxf(fmaf(acc[a][1], s, t0), 0.f);
      float r2 = fmaxf(fmaf(acc[a][2], s, t0), 0.f);
      y[((size_t)b*32 + co)*500 + lp] = fmaxf(r0, fmaxf(r1, r2));
    }
  }
}

// ---------------- conv2 + BN + ReLU + maxpool3 ----------------
// in (512,32,500), W2 (64,32,5), s2 p2 -> (512,64,250) -> pool -> (512,64,83)
__global__ __launch_bounds__(512) void k_conv2(
    const float* __restrict__ y1, const float* __restrict__ W,
    const float* __restrict__ bias, const float* __restrict__ g,
    const float* __restrict__ beta, const float* __restrict__ m,
    const float* __restrict__ vv, float* __restrict__ y2)
{
  __shared__ float xt[32*504];
  __shared__ float wt[160*68];
  __shared__ float sc[64], sh[64];
  const int b = blockIdx.x, tid = threadIdx.x;
  const float* xb = y1 + (size_t)b*32*500;
  for (int i = tid; i < 32*504; i += 512){
    int ci = i/504, p = i - ci*504;
    int gp = p - 2;
    xt[i] = (gp >= 0 && gp < 500) ? xb[ci*500 + gp] : 0.f;
  }
  for (int i = tid; i < 10240; i += 512){
    int co = i/160, r = i - co*160;
    wt[r*68 + co] = W[i];
  }
  if (tid < 64){
    float s = g[tid]*rsqrtf(vv[tid]+1e-5f);
    sc[tid] = s; sh[tid] = (bias[tid]-m[tid])*s + beta[tid];
  }
  __syncthreads();
  const int lpl = tid & 127, cog = tid >> 7, co0 = cog*16;
  if (lpl < 83){
    float acc[16][3];
    #pragma unroll
    for (int a=0;a<16;a++){ acc[a][0]=0.f; acc[a][1]=0.f; acc[a][2]=0.f; }
    for (int ci = 0; ci < 32; ci++){
      const float2* xp = (const float2*)&xt[ci*504 + 6*lpl];
      float xx[10];
      #pragma unroll
      for (int j=0;j<5;j++){ float2 t2 = xp[j]; xx[2*j]=t2.x; xx[2*j+1]=t2.y; }
      #pragma unroll
      for (int k=0;k<5;k++){
        const float4* wp4 = (const float4*)&wt[(ci*5+k)*68 + co0];
        float4 w0=wp4[0], w1=wp4[1], w2=wp4[2], w3=wp4[3];
        float w16[16] = {w0.x,w0.y,w0.z,w0.w, w1.x,w1.y,w1.z,w1.w,
                         w2.x,w2.y,w2.z,w2.w, w3.x,w3.y,w3.z,w3.w};
        #pragma unroll
        for (int a=0;a<16;a++){
          acc[a][0] = fmaf(w16[a], xx[k],   acc[a][0]);
          acc[a][1] = fmaf(w16[a], xx[k+2], acc[a][1]);
          acc[a][2] = fmaf(w16[a], xx[k+4], acc[a][2]);
        }
      }
    }
    #pragma unroll
    for (int a=0;a<16;a++){
      int co = co0 + a;
      float s = sc[co], t0 = sh[co];
      float r0 = fmaxf(fmaf(acc[a][0], s, t0), 0.f);
      float r1 = fmaxf(fmaf(acc[a][1], s, t0), 0.f);
      float r2 = fmaxf(fmaf(acc[a][2], s, t0), 0.f);
      y2[((size_t)b*64 + co)*83 + lpl] = fmaxf(r0, fmaxf(r1, r2));
    }
  }
}

// ---------------- conv3 + BN + ReLU + mean ----------------
// in (512,64,83), W3 (128,64,3), s2 p1 -> (512,128,42) -> mean -> (512,128)
// block: 512 thr = 64 lanes(co-pair) x {bi(2) x lq(4)}; 2 batches/block
__global__ __launch_bounds__(512) void k_conv3(
    const float* __restrict__ y2, const float* __restrict__ W,
    const float* __restrict__ bias, const float* __restrict__ g,
    const float* __restrict__ beta, const float* __restrict__ m,
    const float* __restrict__ vv, float* __restrict__ feat)
{
  __shared__ float xt[2*64*92];
  __shared__ float wt[192*130];
  __shared__ float sc[128], sh[128];
  __shared__ float ps[2][4][128];
  const int b0 = blockIdx.x*2, tid = threadIdx.x;
  for (int i = tid; i < 11776; i += 512){
    int bi = i/5888, r = i - bi*5888;
    int ci = r/92, p = r - ci*92;
    int gp = p - 1;
    xt[i] = (gp >= 0 && gp < 83) ? y2[((size_t)(b0+bi)*64 + ci)*83 + gp] : 0.f;
  }
  for (int i = tid; i < 24576; i += 512){
    int co = i/192, r = i - co*192;
    wt[r*130 + co] = W[i];
  }
  if (tid < 128){
    float s = g[tid]*rsqrtf(vv[tid]+1e-5f);
    sc[tid] = s; sh[tid] = (bias[tid]-m[tid])*s + beta[tid];
  }
  __syncthreads();
  const int lane = tid & 63, wvi = tid >> 6;
  const int bi = wvi >> 2, lq = wvi & 3;
  const int coA = 2*lane;
  const int nl = (lq == 3) ? 9 : 11;        // l = 11*lq + i, valid l < 42
  float acc[2][11];
  #pragma unroll
  for (int i=0;i<11;i++){ acc[0][i]=0.f; acc[1][i]=0.f; }
  for (int ci = 0; ci < 64; ci++){
    const float2* xp = (const float2*)&xt[(bi*64 + ci)*92 + 22*lq];
    float xx[26];
    #pragma unroll
    for (int j=0;j<13;j++){ float2 t2 = xp[j]; xx[2*j]=t2.x; xx[2*j+1]=t2.y; }
    #pragma unroll
    for (int k=0;k<3;k++){
      float2 w2 = *(const float2*)&wt[(ci*3+k)*130 + coA];
      #pragma unroll
      for (int i=0;i<11;i++){
        acc[0][i] = fmaf(w2.x, xx[2*i+k], acc[0][i]);
        acc[1][i] = fmaf(w2.y, xx[2*i+k], acc[1][i]);
      }
    }
  }
  float scA = sc[coA], shA = sh[coA], scB = sc[coA+1], shB = sh[coA+1];
  float sA = 0.f, sB = 0.f;
  for (int i=0;i<nl;i++){
    sA += fmaxf(fmaf(acc[0][i], scA, shA), 0.f);
    sB += fmaxf(fmaf(acc[1][i], scB, shB), 0.f);
  }
  ps[bi][lq][coA]   = sA;
  ps[bi][lq][coA+1] = sB;
  __syncthreads();
  if (tid < 256){
    int bb = tid >> 7, co = tid & 127;
    feat[(size_t)(b0+bb)*128 + co] =
      (ps[bb][0][co]+ps[bb][1][co]+ps[bb][2][co]+ps[bb][3][co]) * (1.f/42.f);
  }
}

// ---------------- fused 2-layer LSTM cell (one decode step) ----------------
__global__ __launch_bounds__(512) void k_cells(
    int t, const float* __restrict__ feat, const float* __restrict__ emb,
    const float* __restrict__ W4T0, const float* __restrict__ W4T1,
    const float* __restrict__ bih0, const float* __restrict__ bhh0,
    const float* __restrict__ bih1, const float* __restrict__ bhh1,
    float* __restrict__ h1, float* __restrict__ c1,
    float* __restrict__ h2, float* __restrict__ c2,
    ull* __restrict__ slots)
{
  __shared__ float xs[4][256];
  __shared__ float zs[4][512];
  __shared__ float h2p[4][128];
  __shared__ int toks[4];
  const int b0 = blockIdx.x*4, tid = threadIdx.x;
  if (tid < 4){
    int tok = 0;
    if (t > 0) tok = 0xFFFF - (int)(slots[b0+tid] & 0xFFFFull);
    slots[b0+tid] = 0ull;
    toks[tid] = tok;
  }
  __syncthreads();
  for (int i = tid; i < 1024; i += 512){
    int bi = i >> 8, j = i & 255;
    float v;
    if (j < 128) v = emb[(size_t)toks[bi]*128 + j];
    else         v = (t==0) ? feat[(size_t)(b0+bi)*128 + (j-128)]
                            : h1[(size_t)(b0+bi)*128 + (j-128)];
    xs[bi][j] = v;
  }
  for (int i = tid; i < 512; i += 512){
    int bi = i >> 7, j = i & 127;
    h2p[bi][j] = (t==0) ? feat[(size_t)(b0+bi)*128 + j] : h2[(size_t)(b0+bi)*128 + j];
  }
  __syncthreads();
  { // layer 1
    float bz = bih0[tid] + bhh0[tid];
    float a0=bz,a1=bz,a2=bz,a3=bz;
    const float4* wbase = (const float4*)W4T0 + tid;
    #pragma unroll 8
    for (int kc=0; kc<64; kc++){
      float4 w  = wbase[kc*512];
      float4 x0 = *(const float4*)&xs[0][4*kc];
      float4 x1 = *(const float4*)&xs[1][4*kc];
      float4 x2 = *(const float4*)&xs[2][4*kc];
      float4 x3 = *(const float4*)&xs[3][4*kc];
      a0 = fmaf(w.x,x0.x,fmaf(w.y,x0.y,fmaf(w.z,x0.z,fmaf(w.w,x0.w,a0))));
      a1 = fmaf(w.x,x1.x,fmaf(w.y,x1.y,fmaf(w.z,x1.z,fmaf(w.w,x1.w,a1))));
      a2 = fmaf(w.x,x2.x,fmaf(w.y,x2.y,fmaf(w.z,x2.z,fmaf(w.w,x2.w,a2))));
      a3 = fmaf(w.x,x3.x,fmaf(w.y,x3.y,fmaf(w.z,x3.z,fmaf(w.w,x3.w,a3))));
    }
    zs[0][tid]=a0; zs[1][tid]=a1; zs[2][tid]=a2; zs[3][tid]=a3;
  }
  __syncthreads();
  { // gates layer 1
    int bi = tid >> 7, j = tid & 127;
    int b = b0 + bi;
    float zi = zs[bi][j], zf = zs[bi][j+128], zg = zs[bi][j+256], zo = zs[bi][j+384];
    float cp = (t==0) ? 0.f : c1[(size_t)b*128 + j];
    float c = sigm(zf)*cp + sigm(zi)*tanhf(zg);
    float hh = sigm(zo)*tanhf(c);
    c1[(size_t)b*128+j] = c;
    h1[(size_t)b*128+j] = hh;
    xs[bi][j] = hh;
    xs[bi][128+j] = h2p[bi][j];
  }
  __syncthreads();
  { // layer 2
    float bz = bih1[tid] + bhh1[tid];
    float a0=bz,a1=bz,a2=bz,a3=bz;
    const float4* wbase = (const float4*)W4T1 + tid;
    #pragma unroll 8
    for (int kc=0; kc<64; kc++){
      float4 w  = wbase[kc*512];
      float4 x0 = *(const float4*)&xs[0][4*kc];
      float4 x1 = *(const float4*)&xs[1][4*kc];
      float4 x2 = *(const float4*)&xs[2][4*kc];
      float4 x3 = *(const float4*)&xs[3][4*kc];
      a0 = fmaf(w.x,x0.x,fmaf(w.y,x0.y,fmaf(w.z,x0.z,fmaf(w.w,x0.w,a0))));
      a1 = fmaf(w.x,x1.x,fmaf(w.y,x1.y,fmaf(w.z,x1.z,fmaf(w.w,x1.w,a1))));
      a2 = fmaf(w.x,x2.x,fmaf(w.y,x2.y,fmaf(w.z,x2.z,fmaf(w.w,x2.w,a2))));
      a3 = fmaf(w.x,x3.x,fmaf(w.y,x3.y,fmaf(w.z,x3.z,fmaf(w.w,x3.w,a3))));
    }
    zs[0][tid]=a0; zs[1][tid]=a1; zs[2][tid]=a2; zs[3][tid]=a3;
  }
  __syncthreads();
  { // gates layer 2
    int bi = tid >> 7, j = tid & 127;
    int b = b0 + bi;
    float zi = zs[bi][j], zf = zs[bi][j+128], zg = zs[bi][j+256], zo = zs[bi][j+384];
    float cp = (t==0) ? 0.f : c2[(size_t)b*128 + j];
    float c = sigm(zf)*cp + sigm(zi)*tanhf(zg);
    float hh = sigm(zo)*tanhf(c);
    c2[(size_t)b*128+j] = c;
    h2[(size_t)b*128+j] = hh;
  }
}

// ---------------- logits + write + argmax ----------------
// block: 256 thr, 1 v/thread, 16 batches; grid (20, 32)
__global__ __launch_bounds__(256) void k_logits(
    int t, const float* __restrict__ h2, const float* __restrict__ Wp4T,
    const float* __restrict__ bp, float* __restrict__ out,
    ull* __restrict__ slots)
{
  __shared__ float hs[16][128];
  __shared__ ull warr[16][4];
  const int b0 = blockIdx.y*16;
  const int v0 = blockIdx.x*256;
  const int tid = threadIdx.x;
  for (int i = tid; i < 2048; i += 256){
    int bi = i >> 7, j = i & 127;
    hs[bi][j] = h2[(size_t)(b0+bi)*128 + j];
  }
  __syncthreads();
  const int v = v0 + tid;
  const bool act = v < VOC;
  const int vc = act ? v : (VOC-1);
  float bv = bp[vc];
  float acc[16];
  #pragma unroll
  for (int i=0;i<16;i++) acc[i] = bv;
  const float4* wbase = (const float4*)Wp4T + vc;
  #pragma unroll 4
  for (int kc=0; kc<32; kc++){
    float4 w = wbase[kc*5000];
    #pragma unroll
    for (int i=0;i<16;i++){
      float4 a = *(const float4*)&hs[i][4*kc];
      acc[i] = fmaf(w.x,a.x,fmaf(w.y,a.y,fmaf(w.z,a.z,fmaf(w.w,a.w,acc[i]))));
    }
  }
  ull best[16];
  if (act){
    #pragma unroll
    for (int i=0;i<16;i++){
      out[((size_t)(b0+i)*TSTEPS + t)*VOC + v] = acc[i];
      best[i] = enc_key(acc[i], v);
    }
  } else {
    #pragma unroll
    for (int i=0;i<16;i++) best[i] = 0ull;
  }
  #pragma unroll
  for (int i=0;i<16;i++){
    ull k = best[i];
    for (int off = 32; off; off >>= 1)
      k = umax64(k, __shfl_xor(k, off, 64));
    best[i] = k;
  }
  int lane = tid & 63, wid = tid >> 6;
  if (lane == 0){
    #pragma unroll
    for (int i=0;i<16;i++) warr[i][wid] = best[i];
  }
  __syncthreads();
  if (tid < 16){
    ull k = umax64(umax64(warr[tid][0], warr[tid][1]),
                   umax64(warr[tid][2], warr[tid][3]));
    atomicMax(&slots[b0+tid], k);
  }
}

extern "C" void kernel_launch(void* const* d_in, const int* in_sizes, int n_in,
                              void* d_out, int out_size, void* d_ws, size_t ws_size,
                              hipStream_t stream)
{
  (void)in_sizes; (void)n_in; (void)out_size; (void)ws_size;
  const float* eeg  = (const float*)d_in[0];
  const float* W1   = (const float*)d_in[2];
  const float* b1   = (const float*)d_in[3];
  const float* g1   = (const float*)d_in[4];
  const float* be1  = (const float*)d_in[5];
  const float* m1   = (const float*)d_in[6];
  const float* v1   = (const float*)d_in[7];
  const float* W2   = (const float*)d_in[8];
  const float* b2   = (const float*)d_in[9];
  const float* g2   = (const float*)d_in[10];
  const float* be2  = (const float*)d_in[11];
  const float* m2   = (const float*)d_in[12];
  const float* v2   = (const float*)d_in[13];
  const float* W3   = (const float*)d_in[14];
  const float* b3   = (const float*)d_in[15];
  const float* g3   = (const float*)d_in[16];
  const float* be3  = (const float*)d_in[17];
  const float* m3   = (const float*)d_in[18];
  const float* v3   = (const float*)d_in[19];
  const float* emb  = (const float*)d_in[20];
  const float* Wih0 = (const float*)d_in[21];
  const float* Whh0 = (const float*)d_in[22];
  const float* bih0 = (const float*)d_in[23];
  const float* bhh0 = (const float*)d_in[24];
  const float* Wih1 = (const float*)d_in[25];
  const float* Whh1 = (const float*)d_in[26];
  const float* bih1 = (const float*)d_in[27];
  const float* bhh1 = (const float*)d_in[28];
  const float* Wp   = (const float*)d_in[29];
  const float* bp   = (const float*)d_in[30];
  float* out = (float*)d_out;

  // conv activations aliased into d_out (fully consumed before first logits write)
  float* y1 = out;                        // 512*32*500 = 8,192,000 f
  float* y2 = out + 8192000;              // 512*64*83  = 2,719,744 f

  float* ws   = (float*)d_ws;
  float* W4T0 = ws;                       // 131072 f
  float* W4T1 = W4T0 + 131072;            // 131072 f
  float* Wp4T = W4T1 + 131072;            // 640000 f
  float* feat = Wp4T + 640000;            // 65536 f
  float* h1   = feat + 65536;
  float* c1   = h1 + 65536;
  float* h2   = c1 + 65536;
  float* c2   = h2 + 65536;
  ull* slots  = (ull*)(c2 + 65536);       // 512 ull

  k_prep<<<881, 256, 0, stream>>>(Wih0, Whh0, Wih1, Whh1, Wp, W4T0, W4T1, Wp4T);
  k_conv1<<<dim3(4, 512), 256, 0, stream>>>(eeg, W1, b1, g1, be1, m1, v1, y1);
  k_conv2<<<512, 512, 0, stream>>>(y1, W2, b2, g2, be2, m2, v2, y2);
  k_conv3<<<256, 512, 0, stream>>>(y2, W3, b3, g3, be3, m3, v3, feat);
  for (int t = 0; t < TSTEPS; t++){
    k_cells<<<128, 512, 0, stream>>>(t, feat, emb, W4T0, W4T1, bih0, bhh0,
                                     bih1, bhh1, h1, c1, h2, c2, slots);
    k_logits<<<dim3(20, 32), 256, 0, stream>>>(t, h2, Wp4T, bp, out, slots);
  }
}